// Round 4
// baseline (45.660 us; speedup 1.0000x reference)
//
#include <hip/hip_runtime.h>

#define N_TOKENS 65536
#define TOK_PER_BLOCK 32
#define TOK_PER_ROUND 8
#define ROUNDS (TOK_PER_BLOCK / TOK_PER_ROUND)

// ---------------------------------------------------------------------------
// Kernel 1: build W[32][128] = fold(core3, core4, core5)
// W[r, j] with j = p*32 + m1*4 + v:
//   W[r,j] = sum_{m2<8} ( sum_{q<16} core3[r,p,q] * core4[q,m1,m2] ) * core5[m2,v]
// core3: [32][4][16], core4: [16][8][8], core5: [8][4][1]
// ---------------------------------------------------------------------------
__global__ void build_w(const float* __restrict__ c3, const float* __restrict__ c4,
                        const float* __restrict__ c5, float* __restrict__ W) {
    int t = blockIdx.x * blockDim.x + threadIdx.x;   // 0..4095
    if (t >= 32 * 128) return;
    int r = t >> 7;
    int j = t & 127;
    int p  = j >> 5;
    int m1 = (j >> 2) & 7;
    int v  = j & 3;
    const float* c3row = c3 + (r * 4 + p) * 16;
    float acc = 0.f;
#pragma unroll
    for (int m2 = 0; m2 < 8; ++m2) {
        float t1 = 0.f;
#pragma unroll
        for (int q = 0; q < 16; ++q)
            t1 += c3row[q] * c4[q * 64 + m1 * 8 + m2];
        acc += t1 * c5[m2 * 4 + v];
    }
    W[r * 128 + j] = acc;
}

// ---------------------------------------------------------------------------
// Kernel 2: main TT-embedding
// per token n: i0,i1,i2 <- idx[n]
//   g1[s] = sum_r core0[i0*32+r] * core1[r*3200 + i1*32 + s]
//   g2[s] = sum_r g1[r]          * core2[r*3200 + i2*32 + s]
//   out[n, j] = sum_r g2[r] * W[r, j]
// ---------------------------------------------------------------------------
__global__ __launch_bounds__(256, 4) void tt_embed(
    const int* __restrict__ idx,
    const float* __restrict__ c0,   // [100][32]
    const float* __restrict__ c1,   // [32][100][32]
    const float* __restrict__ c2,   // [32][100][32]
    const float* __restrict__ Wg,   // [32][128]
    float* __restrict__ out)        // [N][128]
{
    __shared__ float Wl[32 * 128];          // 16 KB
    __shared__ float g2l[TOK_PER_ROUND][32];

    const int t = threadIdx.x;

    // stage W into LDS: 4096 floats = 1024 float4, 256 threads x 4
    {
        const float4* Wg4 = (const float4*)Wg;
        float4* Wl4 = (float4*)Wl;
#pragma unroll
        for (int i = 0; i < 4; ++i)
            Wl4[t + i * 256] = Wg4[t + i * 256];
    }
    __syncthreads();

    const int tt = t >> 5;    // token-in-round (0..7)
    const int s  = t & 31;    // lane within 32-group / col4 in out phase
    const int blockBase = blockIdx.x * TOK_PER_BLOCK;

    for (int round = 0; round < ROUNDS; ++round) {
        const int n = blockBase + round * TOK_PER_ROUND + tt;
        const int iv = idx[n];
        const int i0  = iv / 10000;
        const int rem = iv - i0 * 10000;
        const int i1  = rem / 100;
        const int i2  = rem - i1 * 100;

        // ---- g1[s] ----
        const float4* c0r4 = (const float4*)(c0 + i0 * 32);
        const float* c1p = c1 + i1 * 32 + s;
        float g1 = 0.f;
#pragma unroll
        for (int r4 = 0; r4 < 8; ++r4) {
            float4 a = c0r4[r4];
            g1 += a.x * c1p[(r4 * 4 + 0) * 3200];
            g1 += a.y * c1p[(r4 * 4 + 1) * 3200];
            g1 += a.z * c1p[(r4 * 4 + 2) * 3200];
            g1 += a.w * c1p[(r4 * 4 + 3) * 3200];
        }

        // ---- g2[s] via intra-32-group broadcast ----
        const float* c2p = c2 + i2 * 32 + s;
        float g2 = 0.f;
#pragma unroll
        for (int r = 0; r < 32; ++r) {
            float g1r = __shfl(g1, r, 32);
            g2 += g1r * c2p[r * 3200];
        }
        g2l[tt][s] = g2;
        __syncthreads();

        // ---- out phase: thread (tt, c4=s) computes out[n, 4s..4s+3] ----
        float4 acc = {0.f, 0.f, 0.f, 0.f};
        const float4* Wl4 = (const float4*)Wl;
#pragma unroll
        for (int r = 0; r < 32; ++r) {
            const float g = g2l[tt][r];
            const float4 w = Wl4[r * 32 + s];
            acc.x += g * w.x;
            acc.y += g * w.y;
            acc.z += g * w.z;
            acc.w += g * w.w;
        }
        float4* outp = (float4*)(out + (size_t)n * 128);
        outp[s] = acc;
        __syncthreads();   // g2l reused next round
    }
}

// ---------------------------------------------------------------------------
extern "C" void kernel_launch(void* const* d_in, const int* in_sizes, int n_in,
                              void* d_out, int out_size, void* d_ws, size_t ws_size,
                              hipStream_t stream) {
    const int*   idx = (const int*)d_in[0];
    const float* c0  = (const float*)d_in[1];
    const float* c1  = (const float*)d_in[2];
    const float* c2  = (const float*)d_in[3];
    const float* c3  = (const float*)d_in[4];
    const float* c4  = (const float*)d_in[5];
    const float* c5  = (const float*)d_in[6];
    float* out = (float*)d_out;
    float* W   = (float*)d_ws;   // 32*128 floats = 16 KB scratch

    hipLaunchKernelGGL(build_w, dim3(16), dim3(256), 0, stream, c3, c4, c5, W);
    hipLaunchKernelGGL(tt_embed, dim3(N_TOKENS / TOK_PER_BLOCK), dim3(256), 0, stream,
                       idx, c0, c1, c2, W, out);
}